// Round 11
// baseline (247.029 us; speedup 1.0000x reference)
//
#include <hip/hip_runtime.h>
#include <hip/hip_bf16.h>

// B=4, N=1024, C=768, H=12, D=64, SCALE=1/8. Inputs fp32, output fp32.
// Internal math bf16 MFMA. fp32->bf16 pre-convert enables global_load_lds(16B).
//
// GLOBAL K-MAJOR TILED LAYOUT for all GEMM operands (Xc, Wqc, Wpc, o_ws):
//   [G][kt][kslot][r][ke]  where G = row/16, r = row%16, kt = k/32,
//   kslot = (k%32)/8, ke = k%8.  One (G,kt) block = 512 elems = 1 KB.
// Staging reads a CONTIGUOUS 1 KB per global_load_lds (base + lane*16B),
// LDS stays linear, MFMA fragment reads are group_base + lane*16B ->
// sequential 1 KB stream, ZERO bank conflicts (verified round 7).

typedef __bf16 bf16x8 __attribute__((ext_vector_type(8)));
typedef __bf16 bf16x4 __attribute__((ext_vector_type(4)));
typedef float  f32x4  __attribute__((ext_vector_type(4)));

__device__ __forceinline__ bf16x8 cvt8(const float* p) {
    f32x4 f0 = *(const f32x4*)p;
    f32x4 f1 = *(const f32x4*)(p + 4);
    bf16x8 r;
    r[0] = (__bf16)f0[0]; r[1] = (__bf16)f0[1]; r[2] = (__bf16)f0[2]; r[3] = (__bf16)f0[3];
    r[4] = (__bf16)f1[0]; r[5] = (__bf16)f1[1]; r[6] = (__bf16)f1[2]; r[7] = (__bf16)f1[3];
    return r;
}

__device__ __forceinline__ void async16(const __bf16* g, __bf16* l) {
    __builtin_amdgcn_global_load_lds(
        (const __attribute__((address_space(1))) void*)g,
        (__attribute__((address_space(3))) void*)l, 16, 0, 0);
}

// ---------------------------------------------------------------------------
// Tiled convert via LDS transpose (round-8 version, unchanged).
// ---------------------------------------------------------------------------
__global__ __launch_bounds__(256)
void cvt4_k(const float* __restrict__ x1, const float* __restrict__ x2,
            const float* __restrict__ wq, const float* __restrict__ wp,
            __bf16* __restrict__ xc, __bf16* __restrict__ wqc,
            __bf16* __restrict__ wpc)
{
    __shared__ __bf16 L[16][776];        // +8 pad
    const int bid = blockIdx.x, t = threadIdx.x;
    const float* src; __bf16* dst; int G;
    if (bid < 256)      { src = x1; dst = xc;            G = bid; }
    else if (bid < 512) { src = x2; dst = xc + 3145728;  G = bid - 256; }
    else if (bid < 656) { src = wq; dst = wqc;           G = bid - 512; }
    else                { src = wp; dst = wpc;           G = bid - 656; }

    const float* sb = src + (size_t)G * 16 * 768;
#pragma unroll
    for (int k = 0; k < 6; k++) {
        int iv = k * 256 + t;            // 0..1535 (f32x8 runs)
        int row = iv / 96, c8 = iv % 96;
        *(bf16x8*)&L[row][c8 * 8] = cvt8(sb + row * 768 + c8 * 8);
    }
    __syncthreads();
    __bf16* db = dst + (size_t)G * 12288;   // G-stripe: 24 kt x 512, contiguous
#pragma unroll
    for (int k = 0; k < 6; k++) {
        int j = k * 256 + t;             // 0..1535 (bf16x8 runs)
        int r = j & 15, ks = (j >> 4) & 3, kt = j >> 6;
        *(bf16x8*)(db + (size_t)j * 8) = *(const bf16x8*)&L[r][kt * 32 + ks * 8];
    }
}

// legacy scalar tiled convert (only used when ws too small for fused Wp path)
__global__ __launch_bounds__(256)
void cvt_kt(const float* __restrict__ src, __bf16* __restrict__ dst, int nrun) {
    int j = blockIdx.x * 256 + threadIdx.x;
    if (j >= nrun) return;
    const int r  = j & 15;
    const int ks = (j >> 4) & 3;
    const int t2 = j >> 6;
    const int kt = t2 % 24;
    const int G  = t2 / 24;
    *(bf16x8*)(dst + (size_t)j * 8) =
        cvt8(src + (size_t)(G * 16 + r) * 768 + kt * 32 + ks * 8);
}

// ---------------------------------------------------------------------------
// QKV GEMM, 128x128 tile, BK=32, 3-buffer counted-vmcnt pipeline on TILED
// operands (round-7 structure, 56.4us, 0 bank conflicts). Unchanged.
// ---------------------------------------------------------------------------
__global__ __launch_bounds__(256)
void gemm_qkv_s(const __bf16* __restrict__ Xc, const __bf16* __restrict__ Wq,
                const float* __restrict__ bias,
                __bf16* __restrict__ qo, __bf16* __restrict__ ko,
                __bf16* __restrict__ vo)
{
    __shared__ __bf16 As[3][128 * 32];   // 24 KB (8 groups x 512 elems)
    __shared__ __bf16 Bs[3][128 * 32];   // 24 KB

    const int t = threadIdx.x, w = t >> 6, lane = t & 63;
    const int l15 = lane & 15, quad = lane >> 4;
    const int wm = w >> 1, wn = w & 1;

    const int bid  = blockIdx.x;          // 0..1151
    const int xcd  = bid & 7;
    const int i6   = bid >> 3;            // 0..143
    const int pair = i6 / 18;             // 0..7
    const int gx   = i6 - pair * 18;      // 0..17
    const int p    = xcd * 8 + pair;      // 0..63
    const int gy   = p & 31;
    const int st   = p >> 5;

    const __bf16* Ab = Xc + (size_t)st * 3145728 + (size_t)(gy * 8) * 24 * 512;
    const __bf16* Bb = Wq + (size_t)(gx * 8) * 24 * 512;

    f32x4 acc[4][4];
#pragma unroll
    for (int mi = 0; mi < 4; mi++)
#pragma unroll
        for (int ni = 0; ni < 4; ni++) acc[mi][ni] = f32x4{0.f, 0.f, 0.f, 0.f};

    const int ga0 = w * 2, ga1 = w * 2 + 1;     // this wave's groups

#define QSTAGE(BUF, KT)                                                          \
    do {                                                                         \
        async16(Ab + ((size_t)ga0 * 24 + (KT)) * 512 + lane * 8,                 \
                &As[BUF][ga0 * 512 + lane * 8]);                                 \
        async16(Ab + ((size_t)ga1 * 24 + (KT)) * 512 + lane * 8,                 \
                &As[BUF][ga1 * 512 + lane * 8]);                                 \
        async16(Bb + ((size_t)ga0 * 24 + (KT)) * 512 + lane * 8,                 \
                &Bs[BUF][ga0 * 512 + lane * 8]);                                 \
        async16(Bb + ((size_t)ga1 * 24 + (KT)) * 512 + lane * 8,                 \
                &Bs[BUF][ga1 * 512 + lane * 8]);                                 \
    } while (0)

    QSTAGE(0, 0);

#pragma unroll 3
    for (int kt = 0; kt < 24; kt++) {
        const int cb = kt % 3;
        if (kt < 23) {
            QSTAGE((kt + 1) % 3, kt + 1);
            asm volatile("s_waitcnt vmcnt(4)" ::: "memory");  // kt landed; kt+1 in flight
        } else {
            asm volatile("s_waitcnt vmcnt(0)" ::: "memory");  // tail drain
        }
        __builtin_amdgcn_s_barrier();
        __builtin_amdgcn_sched_barrier(0);

        bf16x8 af[4], bfr[4];
#pragma unroll
        for (int mi = 0; mi < 4; mi++)
            af[mi] = *(const bf16x8*)&As[cb][(wm * 4 + mi) * 512 + lane * 8];
#pragma unroll
        for (int ni = 0; ni < 4; ni++)
            bfr[ni] = *(const bf16x8*)&Bs[cb][(wn * 4 + ni) * 512 + lane * 8];
#pragma unroll
        for (int mi = 0; mi < 4; mi++)
#pragma unroll
            for (int ni = 0; ni < 4; ni++)
                acc[mi][ni] = __builtin_amdgcn_mfma_f32_16x16x32_bf16(af[mi], bfr[ni], acc[mi][ni], 0, 0, 0);
    }
#undef QSTAGE

    const int which = (gx * 128) / 768;   // uniform per block (tile never spans)

    if (which == 2) {
#pragma unroll
        for (int ni = 0; ni < 4; ni++) {
            int j = gx * 128 + wn * 64 + ni * 16 + l15;
            int c = j - 1536;
            int h = c >> 6, d = c & 63;
            float bj = bias[j];
#pragma unroll
            for (int mi = 0; mi < 4; mi++) {
                int row0 = gy * 128 + wm * 64 + mi * 16 + quad * 4;
                int b = row0 >> 10, tok0 = row0 & 1023;
                bf16x4 pv;
#pragma unroll
                for (int r = 0; r < 4; r++) pv[r] = (__bf16)(acc[mi][ni][r] + bj);
                *(bf16x4*)&vo[((size_t)((st * 4 + b) * 12 + h) * 64 + d) * 1024 + tok0] = pv;
            }
        }
    } else {
#pragma unroll
        for (int ni = 0; ni < 4; ni++) {
            int j     = gx * 128 + wn * 64 + ni * 16 + l15;   // 0..1535
            int c     = j - which * 768;
            int h = c >> 6, d = c & 63;
            float bj  = bias[j];
#pragma unroll
            for (int mi = 0; mi < 4; mi++) {
#pragma unroll
                for (int r = 0; r < 4; r++) {
                    int row = gy * 128 + wm * 64 + mi * 16 + quad * 4 + r;
                    int b = row >> 10, tok = row & 1023;
                    float val = acc[mi][ni][r] + bj;
                    if (which == 0)
                        qo[((size_t)((st * 4 + b) * 12 + h) * 1024 + tok) * 64 + d] = (__bf16)(val * 0.125f);
                    else
                        ko[((size_t)((st * 4 + b) * 12 + h) * 1024 + tok) * 64 + d] = (__bf16)val;
                }
            }
        }
    }
}

// ---------------------------------------------------------------------------
// proj GEMM, 64x128 tile, BK=32, 3-buffer counted-vmcnt pipeline, TILED
// operands, grid 6x128 = 768 = 3/CU balanced (round-8 version, unchanged).
// ---------------------------------------------------------------------------
__global__ __launch_bounds__(256)
void gemm_proj(const __bf16* __restrict__ A, const __bf16* __restrict__ Wp,
               const float* __restrict__ bias, float* __restrict__ out)
{
    __shared__ __bf16 As[3][64 * 32];    // 4 KB per buf
    __shared__ __bf16 Bs[3][128 * 32];   // 8 KB per buf

    const int t = threadIdx.x, w = t >> 6, lane = t & 63;
    const int l15 = lane & 15, quad = lane >> 4;
    const int wm = w >> 1, wn = w & 1;
    const int gx = blockIdx.x, gy = blockIdx.y;   // 6 x 128

    const __bf16* Ab = A  + (size_t)(gy * 4) * 24 * 512;
    const __bf16* Bb = Wp + (size_t)(gx * 8) * 24 * 512;

    f32x4 acc[2][4];
#pragma unroll
    for (int mi = 0; mi < 2; mi++)
#pragma unroll
        for (int ni = 0; ni < 4; ni++) acc[mi][ni] = f32x4{0.f, 0.f, 0.f, 0.f};

#define PSTAGE(BUF, KT)                                                          \
    do {                                                                         \
        async16(Ab + ((size_t)w * 24 + (KT)) * 512 + lane * 8,                   \
                &As[BUF][w * 512 + lane * 8]);                                   \
        async16(Bb + ((size_t)(w * 2) * 24 + (KT)) * 512 + lane * 8,             \
                &Bs[BUF][(w * 2) * 512 + lane * 8]);                             \
        async16(Bb + ((size_t)(w * 2 + 1) * 24 + (KT)) * 512 + lane * 8,         \
                &Bs[BUF][(w * 2 + 1) * 512 + lane * 8]);                         \
    } while (0)

    PSTAGE(0, 0);

#pragma unroll 3
    for (int kt = 0; kt < 24; kt++) {
        const int cb = kt % 3;
        if (kt < 23) {
            PSTAGE((kt + 1) % 3, kt + 1);
            asm volatile("s_waitcnt vmcnt(3)" ::: "memory");
        } else {
            asm volatile("s_waitcnt vmcnt(0)" ::: "memory");
        }
        __builtin_amdgcn_s_barrier();
        __builtin_amdgcn_sched_barrier(0);

        bf16x8 af[2], bfr[4];
#pragma unroll
        for (int mi = 0; mi < 2; mi++)
            af[mi] = *(const bf16x8*)&As[cb][(wm * 2 + mi) * 512 + lane * 8];
#pragma unroll
        for (int ni = 0; ni < 4; ni++)
            bfr[ni] = *(const bf16x8*)&Bs[cb][(wn * 4 + ni) * 512 + lane * 8];
#pragma unroll
        for (int mi = 0; mi < 2; mi++)
#pragma unroll
            for (int ni = 0; ni < 4; ni++)
                acc[mi][ni] = __builtin_amdgcn_mfma_f32_16x16x32_bf16(af[mi], bfr[ni], acc[mi][ni], 0, 0, 0);
    }
#undef PSTAGE

#pragma unroll
    for (int ni = 0; ni < 4; ni++) {
        int col  = gx * 128 + wn * 64 + ni * 16 + l15;
        float bj = bias[col];
#pragma unroll
        for (int mi = 0; mi < 2; mi++)
#pragma unroll
            for (int r = 0; r < 4; r++) {
                int row = gy * 64 + (wm * 2 + mi) * 16 + quad * 4 + r;  // 0..8191
                out[(size_t)row * 768 + col] = acc[mi][ni][r] + bj;
            }
    }
}

// ---------------------------------------------------------------------------
// Dual-stream flash attention v4: 1-WAVE BLOCKS, ZERO BARRIERS.
// R9 proved occupancy is not the constraint; R1 proved prefetch-hiding under
// barriers is ~0. The cost is the barrier-coupled per-iteration chain -> remove
// barriers entirely: one 64-lane wave per block owns 32 q-rows (2 sets), all
// staging-ordering is wave-local counted vmcnt. K and V each SINGLE-buffered
// with post-consumption prefetch: K(kt+1) issued right after QK(kt) (lands
// during exp+PV); V(kt+1) issued right after PV(kt) (lands during QK+exp of
// kt+1). Steady-state waits are vmcnt(8) (8 older loads done, 8 newest in
// flight), vmcnt(0) only at the tail. WAR on LDS: ds_reads of the buffer
// being overwritten retired before the stage issue (lgkmcnt(0) +
// sched_barrier(0) pin, rule 18). DS queue is in-order per wave -> Ps
// write->read needs no fence beyond compiler lgkmcnt.
// LDS 20.5 KB -> 7 blocks/CU; grid 1536 (32 row-tiles x 48 bh) ALL resident.
// bh%8 = XCD (48%8==0) -> K/V L2-locality preserved.
// ---------------------------------------------------------------------------
__global__ __launch_bounds__(64)
void attn_k(const __bf16* __restrict__ qws, const __bf16* __restrict__ kws,
            const __bf16* __restrict__ vws, __bf16* __restrict__ ows)
{
    __shared__ __bf16 KF[2][2][2][512];  // [s][kk][mi2][lane*8]  8 KB
    __shared__ __bf16 VF[2][4][512];     // [s][mi4][lane*8]      8 KB
    __shared__ __bf16 PS[2][16 * 72];    // [set]                 4.5 KB

    const int g  = blockIdx.x;
    const int qt = g / 48;              // 0..31 (32-row q tiles)
    const int bh = g % 48;              // 0..47
    const int b = bh / 12, h = bh % 12;
    const int lane = threadIdx.x;       // 0..63 (one wave)
    const int l15 = lane & 15, quad = lane >> 4;

    const size_t head_off = (size_t)bh * 65536;          // 1024*64
    const size_t ss       = (size_t)48 * 65536;          // stream stride

    const __bf16* kbase = kws + head_off;
    const __bf16* vbase = vws + head_off;

#define STAGE_K(KEYB)                                                           \
    do {                                                                        \
        _Pragma("unroll")                                                       \
        for (int i = 0; i < 8; i++) {                                           \
            const int s = i >> 2, kk = (i >> 1) & 1, mi = i & 1;                \
            async16(kbase + s * ss + (size_t)((KEYB) + mi * 16 + l15) * 64      \
                        + kk * 32 + quad * 8,                                   \
                    &KF[s][kk][mi][lane * 8]);                                  \
        }                                                                       \
    } while (0)
#define STAGE_V(KEYB)                                                           \
    do {                                                                        \
        _Pragma("unroll")                                                       \
        for (int i = 0; i < 8; i++) {                                           \
            const int s = i >> 2, mi = i & 3;                                   \
            async16(vbase + s * ss + (size_t)(mi * 16 + l15) * 1024             \
                        + (KEYB) + quad * 8,                                    \
                    &VF[s][mi][lane * 8]);                                      \
        }                                                                       \
    } while (0)

    // prologue: stage K(0), V(0); load Q; drain everything once -> loop
    // counting starts at 0 outstanding (clean vmcnt bookkeeping).
    STAGE_K(0);
    STAGE_V(0);

    bf16x8 qf[2][2][2];
#pragma unroll
    for (int set = 0; set < 2; set++)
#pragma unroll
        for (int s = 0; s < 2; s++)
#pragma unroll
            for (int kk = 0; kk < 2; kk++)
                qf[set][s][kk] = *(const bf16x8*)(qws + s * ss + head_off
                    + (size_t)(qt * 32 + set * 16 + l15) * 64 + kk * 32 + quad * 8);

    float lsum[2] = {0.f, 0.f};
    f32x4 accO[2][2][4];
#pragma unroll
    for (int set = 0; set < 2; set++)
#pragma unroll
        for (int s = 0; s < 2; s++)
#pragma unroll
            for (int mi = 0; mi < 4; mi++) accO[set][s][mi] = f32x4{0.f, 0.f, 0.f, 0.f};

    asm volatile("s_waitcnt vmcnt(0)" ::: "memory");   // Q + K0 + V0 all landed
    __builtin_amdgcn_sched_barrier(0);

    for (int kt = 0; kt < 32; kt++) {
        // ---- K(kt) guaranteed: steady state = 8 older loads done (K this
        // tile), 8 newest (V this tile) still allowed in flight.
        if (kt > 0) {
            asm volatile("s_waitcnt vmcnt(8)" ::: "memory");
            __builtin_amdgcn_sched_barrier(0);
        }

        // ---- QK^T: S = S1 + S2 in one accumulation chain
        f32x4 accS[2][2];
#pragma unroll
        for (int set = 0; set < 2; set++)
#pragma unroll
            for (int mi = 0; mi < 2; mi++) accS[set][mi] = f32x4{0.f, 0.f, 0.f, 0.f};
        __builtin_amdgcn_s_setprio(1);
#pragma unroll
        for (int s = 0; s < 2; s++)
#pragma unroll
            for (int kk = 0; kk < 2; kk++) {
                bf16x8 kf0 = *(const bf16x8*)&KF[s][kk][0][lane * 8];
                bf16x8 kf1 = *(const bf16x8*)&KF[s][kk][1][lane * 8];
#pragma unroll
                for (int set = 0; set < 2; set++) {
                    accS[set][0] = __builtin_amdgcn_mfma_f32_16x16x32_bf16(kf0, qf[set][s][kk], accS[set][0], 0, 0, 0);
                    accS[set][1] = __builtin_amdgcn_mfma_f32_16x16x32_bf16(kf1, qf[set][s][kk], accS[set][1], 0, 0, 0);
                }
            }
        __builtin_amdgcn_s_setprio(0);

        // ---- prefetch K(kt+1) into the SAME buffer: kf ds_reads retired
        // (lgkmcnt(0)), so the WAR is closed; the 8 loads get exp+PV+QK time
        // to land before the next iteration's vmcnt(8).
        if (kt < 31) {
            asm volatile("s_waitcnt lgkmcnt(0)" ::: "memory");
            __builtin_amdgcn_sched_barrier(0);
            STAGE_K((kt + 1) * 32);
        }

        // ---- softmax numerator (no-max; scores bounded)
#pragma unroll
        for (int set = 0; set < 2; set++) {
            float rs = 0.f;
#pragma unroll
            for (int mi = 0; mi < 2; mi++) {
                bf16x4 pk;
#pragma unroll
                for (int r = 0; r < 4; r++) {
                    float pv = __expf(accS[set][mi][r]);
                    pk[r] = (__bf16)pv;
                    rs += pv;
                }
                *(bf16x4*)&PS[set][l15 * 72 + mi * 16 + quad * 4] = pk;
            }
            lsum[set] += rs;
        }

        // ---- V(kt) guaranteed: oldest 8 outstanding (V this tile) done,
        // K(kt+1)'s 8 still in flight. Tail: nothing else outstanding.
        if (kt < 31) {
            asm volatile("s_waitcnt vmcnt(8)" ::: "memory");
        } else {
            asm volatile("s_waitcnt vmcnt(0)" ::: "memory");
        }
        __builtin_amdgcn_sched_barrier(0);

        // ---- PV (O^T = V^T @ P^T); each vf read feeds both q-sets
        bf16x8 pa0 = *(const bf16x8*)&PS[0][l15 * 72 + quad * 8];
        bf16x8 pa1 = *(const bf16x8*)&PS[1][l15 * 72 + quad * 8];
        __builtin_amdgcn_s_setprio(1);
#pragma unroll
        for (int s = 0; s < 2; s++)
#pragma unroll
            for (int mi = 0; mi < 4; mi++) {
                bf16x8 vf = *(const bf16x8*)&VF[s][mi][lane * 8];
                accO[0][s][mi] = __builtin_amdgcn_mfma_f32_16x16x32_bf16(vf, pa0, accO[0][s][mi], 0, 0, 0);
                accO[1][s][mi] = __builtin_amdgcn_mfma_f32_16x16x32_bf16(vf, pa1, accO[1][s][mi], 0, 0, 0);
            }
        __builtin_amdgcn_s_setprio(0);

        // ---- prefetch V(kt+1): vf ds_reads retired (lgkmcnt(0)); loads get
        // next iteration's QK+exp time to land before its pre-PV vmcnt(8).
        if (kt < 31) {
            asm volatile("s_waitcnt lgkmcnt(0)" ::: "memory");
            __builtin_amdgcn_sched_barrier(0);
            STAGE_V((kt + 1) * 32);
        }
    }
#undef STAGE_K
#undef STAGE_V

#pragma unroll
    for (int set = 0; set < 2; set++) {
        float l = lsum[set];
        l += __shfl_xor(l, 16);
        l += __shfl_xor(l, 32);
        float il = 1.f / l;

        const int tok = qt * 32 + set * 16 + l15;
#pragma unroll
        for (int s = 0; s < 2; s++)
#pragma unroll
            for (int mi = 0; mi < 4; mi++) {
                bf16x4 ov;
#pragma unroll
                for (int r = 0; r < 4; r++) ov[r] = (__bf16)(accO[set][s][mi][r] * il);
                const int row = (s * 4 + b) * 1024 + tok;
                const int c   = h * 64 + mi * 16 + quad * 4;
                const size_t off = ((size_t)(row >> 4) * 24 + (c >> 5)) * 512
                                 + ((c >> 3) & 3) * 128 + (row & 15) * 8 + (c & 7);
                *(bf16x4*)&ows[off] = ov;
            }
    }
}

// ---------------------------------------------------------------------------
extern "C" void kernel_launch(void* const* d_in, const int* in_sizes, int n_in,
                              void* d_out, int out_size, void* d_ws, size_t ws_size,
                              hipStream_t stream)
{
    const float* x1    = (const float*)d_in[0];
    const float* x2    = (const float*)d_in[1];
    const float* Wqkv  = (const float*)d_in[2];
    const float* bqkv  = (const float*)d_in[3];
    const float* Wproj = (const float*)d_in[4];
    const float* bproj = (const float*)d_in[5];
    float* out = (float*)d_out;

    const size_t qkv_elems = (size_t)2 * 4 * 12 * 1024 * 64;   // 6,291,456
    __bf16* q_ws = (__bf16*)d_ws;
    __bf16* k_ws = q_ws + qkv_elems;
    __bf16* v_ws = k_ws + qkv_elems;
    __bf16* pool = v_ws + qkv_elems;
    __bf16* o_ws = pool;                // 8192*768 tiled (attn out)
    __bf16* Wqc  = pool + 3145728;      // 2304*768 tiled (dead after QKV GEMM)
    __bf16* Xc   = (__bf16*)d_out;      // x1c | x2c tiled (scratch in out buf)

    const bool big = ws_size >= (size_t)(4 * qkv_elems + 589824) * sizeof(__bf16);
    __bf16* Wpc = big ? (pool + qkv_elems)   // past proven footprint
                      : q_ws;                // legacy: q dead after attn

    // 1) fused fp32->bf16 tiled converts via LDS transpose
    cvt4_k<<<big ? 704 : 656, 256, 0, stream>>>(x1, x2, Wqkv, Wproj, Xc, Wqc, Wpc);
    // 2) QKV GEMM, tiled operands, XCD-ownership swizzle, 3-buf counted-vmcnt
    gemm_qkv_s<<<1152, 256, 0, stream>>>(Xc, Wqc, bqkv, q_ws, k_ws, v_ws);
    // 3) attention v4: 1-wave blocks, zero barriers, wave-local counted vmcnt
    attn_k<<<1536, 64, 0, stream>>>(q_ws, k_ws, v_ws, o_ws);
    // 4) legacy tiled proj weight convert only if ws too small
    if (!big) cvt_kt<<<288, 256, 0, stream>>>(Wproj, Wpc, 73728);
    // 5) proj GEMM, 64x128 tiles, grid 6x128 = 768 = 3/CU balanced
    gemm_proj<<<dim3(6, 128), 256, 0, stream>>>(o_ws, Wpc, bproj, out);
}

// Round 13
// 210.665 us; speedup vs baseline: 1.1726x; 1.1726x over previous
//
#include <hip/hip_runtime.h>
#include <hip/hip_bf16.h>

// B=4, N=1024, C=768, H=12, D=64, SCALE=1/8. Inputs fp32, output fp32.
// Internal math bf16 MFMA. fp32->bf16 pre-convert enables global_load_lds(16B).
//
// GLOBAL K-MAJOR TILED LAYOUT for all GEMM operands (Xc, Wqc, Wpc, o_ws):
//   [G][kt][kslot][r][ke]  where G = row/16, r = row%16, kt = k/32,
//   kslot = (k%32)/8, ke = k%8.  One (G,kt) block = 512 elems = 1 KB.
// Staging reads a CONTIGUOUS 1 KB per global_load_lds (base + lane*16B),
// LDS stays linear, MFMA fragment reads are group_base + lane*16B ->
// sequential 1 KB stream, ZERO bank conflicts (verified round 7).

typedef __bf16 bf16x8 __attribute__((ext_vector_type(8)));
typedef __bf16 bf16x4 __attribute__((ext_vector_type(4)));
typedef float  f32x4  __attribute__((ext_vector_type(4)));

__device__ __forceinline__ bf16x8 cvt8(const float* p) {
    f32x4 f0 = *(const f32x4*)p;
    f32x4 f1 = *(const f32x4*)(p + 4);
    bf16x8 r;
    r[0] = (__bf16)f0[0]; r[1] = (__bf16)f0[1]; r[2] = (__bf16)f0[2]; r[3] = (__bf16)f0[3];
    r[4] = (__bf16)f1[0]; r[5] = (__bf16)f1[1]; r[6] = (__bf16)f1[2]; r[7] = (__bf16)f1[3];
    return r;
}

__device__ __forceinline__ void async16(const __bf16* g, __bf16* l) {
    __builtin_amdgcn_global_load_lds(
        (const __attribute__((address_space(1))) void*)g,
        (__attribute__((address_space(3))) void*)l, 16, 0, 0);
}

// ---------------------------------------------------------------------------
// Tiled convert via LDS transpose (round-8 version, unchanged).
// ---------------------------------------------------------------------------
__global__ __launch_bounds__(256)
void cvt4_k(const float* __restrict__ x1, const float* __restrict__ x2,
            const float* __restrict__ wq, const float* __restrict__ wp,
            __bf16* __restrict__ xc, __bf16* __restrict__ wqc,
            __bf16* __restrict__ wpc)
{
    __shared__ __bf16 L[16][776];        // +8 pad
    const int bid = blockIdx.x, t = threadIdx.x;
    const float* src; __bf16* dst; int G;
    if (bid < 256)      { src = x1; dst = xc;            G = bid; }
    else if (bid < 512) { src = x2; dst = xc + 3145728;  G = bid - 256; }
    else if (bid < 656) { src = wq; dst = wqc;           G = bid - 512; }
    else                { src = wp; dst = wpc;           G = bid - 656; }

    const float* sb = src + (size_t)G * 16 * 768;
#pragma unroll
    for (int k = 0; k < 6; k++) {
        int iv = k * 256 + t;            // 0..1535 (f32x8 runs)
        int row = iv / 96, c8 = iv % 96;
        *(bf16x8*)&L[row][c8 * 8] = cvt8(sb + row * 768 + c8 * 8);
    }
    __syncthreads();
    __bf16* db = dst + (size_t)G * 12288;   // G-stripe: 24 kt x 512, contiguous
#pragma unroll
    for (int k = 0; k < 6; k++) {
        int j = k * 256 + t;             // 0..1535 (bf16x8 runs)
        int r = j & 15, ks = (j >> 4) & 3, kt = j >> 6;
        *(bf16x8*)(db + (size_t)j * 8) = *(const bf16x8*)&L[r][kt * 32 + ks * 8];
    }
}

// legacy scalar tiled convert (only used when ws too small for fused Wp path)
__global__ __launch_bounds__(256)
void cvt_kt(const float* __restrict__ src, __bf16* __restrict__ dst, int nrun) {
    int j = blockIdx.x * 256 + threadIdx.x;
    if (j >= nrun) return;
    const int r  = j & 15;
    const int ks = (j >> 4) & 3;
    const int t2 = j >> 6;
    const int kt = t2 % 24;
    const int G  = t2 / 24;
    *(bf16x8*)(dst + (size_t)j * 8) =
        cvt8(src + (size_t)(G * 16 + r) * 768 + kt * 32 + ks * 8);
}

// ---------------------------------------------------------------------------
// QKV GEMM, 128x128 tile, BK=32, TWO-buffer counted-vmcnt pipeline on TILED
// operands. LDS = 32 KB EXACTLY -> 5 blocks/CU (1280 slots >= grid 1152) ->
// SINGLE-round makespan (the 48 KB 3-buffer variant ran 3/CU = 768 slots ->
// 1.5 rounds, the hidden ~1.5x stretch behind the 56us plateau).
// Race ledger (2 buffers need 2 barriers/iter): iter k stages buf[(k+1)%2];
// iter k-1's readers used that same buffer; barrier B at the end of each
// iteration separates them (reads are consumed by MFMA issue before B).
// Counted vmcnt(4) before barrier A keeps next tile's 4 loads in flight;
// vmcnt(0) only at the tail.
// ---------------------------------------------------------------------------
__global__ __launch_bounds__(256)
void gemm_qkv_s(const __bf16* __restrict__ Xc, const __bf16* __restrict__ Wq,
                const float* __restrict__ bias,
                __bf16* __restrict__ qo, __bf16* __restrict__ ko,
                __bf16* __restrict__ vo)
{
    __shared__ __bf16 As[2][128 * 32];   // 16 KB
    __shared__ __bf16 Bs[2][128 * 32];   // 16 KB

    const int t = threadIdx.x, w = t >> 6, lane = t & 63;
    const int l15 = lane & 15, quad = lane >> 4;
    const int wm = w >> 1, wn = w & 1;

    const int bid  = blockIdx.x;          // 0..1151
    const int xcd  = bid & 7;
    const int i6   = bid >> 3;            // 0..143
    const int pair = i6 / 18;             // 0..7
    const int gx   = i6 - pair * 18;      // 0..17
    const int p    = xcd * 8 + pair;      // 0..63
    const int gy   = p & 31;
    const int st   = p >> 5;

    const __bf16* Ab = Xc + (size_t)st * 3145728 + (size_t)(gy * 8) * 24 * 512;
    const __bf16* Bb = Wq + (size_t)(gx * 8) * 24 * 512;

    f32x4 acc[4][4];
#pragma unroll
    for (int mi = 0; mi < 4; mi++)
#pragma unroll
        for (int ni = 0; ni < 4; ni++) acc[mi][ni] = f32x4{0.f, 0.f, 0.f, 0.f};

    const int ga0 = w * 2, ga1 = w * 2 + 1;     // this wave's groups

#define QSTAGE(BUF, KT)                                                          \
    do {                                                                         \
        async16(Ab + ((size_t)ga0 * 24 + (KT)) * 512 + lane * 8,                 \
                &As[BUF][ga0 * 512 + lane * 8]);                                 \
        async16(Ab + ((size_t)ga1 * 24 + (KT)) * 512 + lane * 8,                 \
                &As[BUF][ga1 * 512 + lane * 8]);                                 \
        async16(Bb + ((size_t)ga0 * 24 + (KT)) * 512 + lane * 8,                 \
                &Bs[BUF][ga0 * 512 + lane * 8]);                                 \
        async16(Bb + ((size_t)ga1 * 24 + (KT)) * 512 + lane * 8,                 \
                &Bs[BUF][ga1 * 512 + lane * 8]);                                 \
    } while (0)

    QSTAGE(0, 0);

#pragma unroll 2
    for (int kt = 0; kt < 24; kt++) {
        const int cb = kt & 1;
        if (kt < 23) {
            QSTAGE(cb ^ 1, kt + 1);
            asm volatile("s_waitcnt vmcnt(4)" ::: "memory");  // kt landed; kt+1 in flight
        } else {
            asm volatile("s_waitcnt vmcnt(0)" ::: "memory");  // tail drain
        }
        __builtin_amdgcn_s_barrier();                         // barrier A: buf cb ready
        __builtin_amdgcn_sched_barrier(0);

        bf16x8 af[4], bfr[4];
#pragma unroll
        for (int mi = 0; mi < 4; mi++)
            af[mi] = *(const bf16x8*)&As[cb][(wm * 4 + mi) * 512 + lane * 8];
#pragma unroll
        for (int ni = 0; ni < 4; ni++)
            bfr[ni] = *(const bf16x8*)&Bs[cb][(wn * 4 + ni) * 512 + lane * 8];
#pragma unroll
        for (int mi = 0; mi < 4; mi++)
#pragma unroll
            for (int ni = 0; ni < 4; ni++)
                acc[mi][ni] = __builtin_amdgcn_mfma_f32_16x16x32_bf16(af[mi], bfr[ni], acc[mi][ni], 0, 0, 0);

        __builtin_amdgcn_s_barrier();                         // barrier B: WAR close
    }
#undef QSTAGE

    const int which = (gx * 128) / 768;   // uniform per block (tile never spans)

    if (which == 2) {
#pragma unroll
        for (int ni = 0; ni < 4; ni++) {
            int j = gx * 128 + wn * 64 + ni * 16 + l15;
            int c = j - 1536;
            int h = c >> 6, d = c & 63;
            float bj = bias[j];
#pragma unroll
            for (int mi = 0; mi < 4; mi++) {
                int row0 = gy * 128 + wm * 64 + mi * 16 + quad * 4;
                int b = row0 >> 10, tok0 = row0 & 1023;
                bf16x4 pv;
#pragma unroll
                for (int r = 0; r < 4; r++) pv[r] = (__bf16)(acc[mi][ni][r] + bj);
                *(bf16x4*)&vo[((size_t)((st * 4 + b) * 12 + h) * 64 + d) * 1024 + tok0] = pv;
            }
        }
    } else {
#pragma unroll
        for (int ni = 0; ni < 4; ni++) {
            int j     = gx * 128 + wn * 64 + ni * 16 + l15;   // 0..1535
            int c     = j - which * 768;
            int h = c >> 6, d = c & 63;
            float bj  = bias[j];
#pragma unroll
            for (int mi = 0; mi < 4; mi++) {
#pragma unroll
                for (int r = 0; r < 4; r++) {
                    int row = gy * 128 + wm * 64 + mi * 16 + quad * 4 + r;
                    int b = row >> 10, tok = row & 1023;
                    float val = acc[mi][ni][r] + bj;
                    if (which == 0)
                        qo[((size_t)((st * 4 + b) * 12 + h) * 1024 + tok) * 64 + d] = (__bf16)(val * 0.125f);
                    else
                        ko[((size_t)((st * 4 + b) * 12 + h) * 1024 + tok) * 64 + d] = (__bf16)val;
                }
            }
        }
    }
}

// ---------------------------------------------------------------------------
// proj GEMM, 64x128 tile, BK=32, 3-buffer counted-vmcnt pipeline, TILED
// operands, grid 6x128 = 768 = 3/CU balanced (round-8 version, unchanged).
// ---------------------------------------------------------------------------
__global__ __launch_bounds__(256)
void gemm_proj(const __bf16* __restrict__ A, const __bf16* __restrict__ Wp,
               const float* __restrict__ bias, float* __restrict__ out)
{
    __shared__ __bf16 As[3][64 * 32];    // 4 KB per buf
    __shared__ __bf16 Bs[3][128 * 32];   // 8 KB per buf

    const int t = threadIdx.x, w = t >> 6, lane = t & 63;
    const int l15 = lane & 15, quad = lane >> 4;
    const int wm = w >> 1, wn = w & 1;
    const int gx = blockIdx.x, gy = blockIdx.y;   // 6 x 128

    const __bf16* Ab = A  + (size_t)(gy * 4) * 24 * 512;
    const __bf16* Bb = Wp + (size_t)(gx * 8) * 24 * 512;

    f32x4 acc[2][4];
#pragma unroll
    for (int mi = 0; mi < 2; mi++)
#pragma unroll
        for (int ni = 0; ni < 4; ni++) acc[mi][ni] = f32x4{0.f, 0.f, 0.f, 0.f};

#define PSTAGE(BUF, KT)                                                          \
    do {                                                                         \
        async16(Ab + ((size_t)w * 24 + (KT)) * 512 + lane * 8,                   \
                &As[BUF][w * 512 + lane * 8]);                                   \
        async16(Bb + ((size_t)(w * 2) * 24 + (KT)) * 512 + lane * 8,             \
                &Bs[BUF][(w * 2) * 512 + lane * 8]);                             \
        async16(Bb + ((size_t)(w * 2 + 1) * 24 + (KT)) * 512 + lane * 8,         \
                &Bs[BUF][(w * 2 + 1) * 512 + lane * 8]);                         \
    } while (0)

    PSTAGE(0, 0);

#pragma unroll 3
    for (int kt = 0; kt < 24; kt++) {
        const int cb = kt % 3;
        if (kt < 23) {
            PSTAGE((kt + 1) % 3, kt + 1);
            asm volatile("s_waitcnt vmcnt(3)" ::: "memory");
        } else {
            asm volatile("s_waitcnt vmcnt(0)" ::: "memory");
        }
        __builtin_amdgcn_s_barrier();
        __builtin_amdgcn_sched_barrier(0);

        bf16x8 af[2], bfr[4];
#pragma unroll
        for (int mi = 0; mi < 2; mi++)
            af[mi] = *(const bf16x8*)&As[cb][(wm * 2 + mi) * 512 + lane * 8];
#pragma unroll
        for (int ni = 0; ni < 4; ni++)
            bfr[ni] = *(const bf16x8*)&Bs[cb][(wn * 4 + ni) * 512 + lane * 8];
#pragma unroll
        for (int mi = 0; mi < 2; mi++)
#pragma unroll
            for (int ni = 0; ni < 4; ni++)
                acc[mi][ni] = __builtin_amdgcn_mfma_f32_16x16x32_bf16(af[mi], bfr[ni], acc[mi][ni], 0, 0, 0);
    }
#undef PSTAGE

#pragma unroll
    for (int ni = 0; ni < 4; ni++) {
        int col  = gx * 128 + wn * 64 + ni * 16 + l15;
        float bj = bias[col];
#pragma unroll
        for (int mi = 0; mi < 2; mi++)
#pragma unroll
            for (int r = 0; r < 4; r++) {
                int row = gy * 64 + (wm * 2 + mi) * 16 + quad * 4 + r;  // 0..8191
                out[(size_t)row * 768 + col] = acc[mi][ni][r] + bj;
            }
    }
}

// ---------------------------------------------------------------------------
// Dual-stream flash attention — round-8 proven version (56.5us): 2 waves/
// block, 2 q-sets/wave, 32-key tiles, double-buffered, 1-deep prefetch, one
// barrier/iter; TILED o_ws epilogue. R9 (occupancy) and R10 (barrier-free)
// both regressed; this structure is the measured optimum.
// ---------------------------------------------------------------------------
__global__ __launch_bounds__(128, 2)
void attn_k(const __bf16* __restrict__ qws, const __bf16* __restrict__ kws,
            const __bf16* __restrict__ vws, __bf16* __restrict__ ows)
{
    __shared__ __bf16 Ks[2][2][2][2][512];  // [buf][s][kk][mi2][lane*8] 16 KB
    __shared__ __bf16 Vs[2][2][4][512];     // [buf][s][mi4][lane*8]     16 KB
    __shared__ __bf16 Ps[2][2][16 * 72];    // [wave][set][row*72]        9 KB

    const int g  = blockIdx.x;
    const int qt = g / 48;              // 0..15
    const int bh = g % 48;              // 0..47
    const int b = bh / 12, h = bh % 12;
    const int t = threadIdx.x, w = t >> 6, lane = t & 63;
    const int l15 = lane & 15, quad = lane >> 4;

    const size_t head_off = (size_t)bh * 65536;          // 1024*64
    const size_t ss       = (size_t)48 * 65536;          // stream stride

    bf16x8 qf[2][2][2];
#pragma unroll
    for (int set = 0; set < 2; set++)
#pragma unroll
        for (int s = 0; s < 2; s++)
#pragma unroll
            for (int kk = 0; kk < 2; kk++)
                qf[set][s][kk] = *(const bf16x8*)(qws + s * ss + head_off
                    + (size_t)(qt * 64 + w * 32 + set * 16 + l15) * 64 + kk * 32 + quad * 8);

    float lsum[2] = {0.f, 0.f};
    f32x4 accO[2][2][4];
#pragma unroll
    for (int set = 0; set < 2; set++)
#pragma unroll
        for (int s = 0; s < 2; s++)
#pragma unroll
            for (int mi = 0; mi < 4; mi++) accO[set][s][mi] = f32x4{0.f, 0.f, 0.f, 0.f};

    const __bf16* kbase = kws + head_off;
    const __bf16* vbase = vws + head_off;

#define STAGE_TILE(BUF, KEYB)                                                   \
    do {                                                                        \
        if (w == 0) {                                                           \
            _Pragma("unroll")                                                   \
            for (int i = 0; i < 8; i++) {                                       \
                const int s = i >> 2, kk = (i >> 1) & 1, mi = i & 1;            \
                async16(kbase + s * ss + (size_t)((KEYB) + mi * 16 + l15) * 64  \
                            + kk * 32 + quad * 8,                               \
                        &Ks[BUF][s][kk][mi][lane * 8]);                         \
            }                                                                   \
        } else {                                                                \
            _Pragma("unroll")                                                   \
            for (int i = 0; i < 8; i++) {                                       \
                const int s = i >> 2, mi = i & 3;                               \
                async16(vbase + s * ss + (size_t)(mi * 16 + l15) * 1024         \
                            + (KEYB) + quad * 8,                                \
                        &Vs[BUF][s][mi][lane * 8]);                             \
            }                                                                   \
        }                                                                       \
    } while (0)

    STAGE_TILE(0, 0);
    __syncthreads();

#pragma unroll 2
    for (int kt = 0; kt < 32; kt++) {
        const int cb = kt & 1, nb = cb ^ 1;

        if (kt < 31) STAGE_TILE(nb, (kt + 1) * 32);

        f32x4 accS[2][2];
#pragma unroll
        for (int set = 0; set < 2; set++)
#pragma unroll
            for (int mi = 0; mi < 2; mi++) accS[set][mi] = f32x4{0.f, 0.f, 0.f, 0.f};
        __builtin_amdgcn_s_setprio(1);
#pragma unroll
        for (int s = 0; s < 2; s++)
#pragma unroll
            for (int kk = 0; kk < 2; kk++) {
                bf16x8 kf0 = *(const bf16x8*)&Ks[cb][s][kk][0][lane * 8];
                bf16x8 kf1 = *(const bf16x8*)&Ks[cb][s][kk][1][lane * 8];
#pragma unroll
                for (int set = 0; set < 2; set++) {
                    accS[set][0] = __builtin_amdgcn_mfma_f32_16x16x32_bf16(kf0, qf[set][s][kk], accS[set][0], 0, 0, 0);
                    accS[set][1] = __builtin_amdgcn_mfma_f32_16x16x32_bf16(kf1, qf[set][s][kk], accS[set][1], 0, 0, 0);
                }
            }
        __builtin_amdgcn_s_setprio(0);

#pragma unroll
        for (int set = 0; set < 2; set++) {
            float rs = 0.f;
#pragma unroll
            for (int mi = 0; mi < 2; mi++) {
                bf16x4 pk;
#pragma unroll
                for (int r = 0; r < 4; r++) {
                    float pv = __expf(accS[set][mi][r]);
                    pk[r] = (__bf16)pv;
                    rs += pv;
                }
                *(bf16x4*)&Ps[w][set][l15 * 72 + mi * 16 + quad * 4] = pk;
            }
            lsum[set] += rs;
        }

        bf16x8 pa0 = *(const bf16x8*)&Ps[w][0][l15 * 72 + quad * 8];
        bf16x8 pa1 = *(const bf16x8*)&Ps[w][1][l15 * 72 + quad * 8];
        __builtin_amdgcn_s_setprio(1);
#pragma unroll
        for (int s = 0; s < 2; s++)
#pragma unroll
            for (int mi = 0; mi < 4; mi++) {
                bf16x8 vf = *(const bf16x8*)&Vs[cb][s][mi][lane * 8];
                accO[0][s][mi] = __builtin_amdgcn_mfma_f32_16x16x32_bf16(vf, pa0, accO[0][s][mi], 0, 0, 0);
                accO[1][s][mi] = __builtin_amdgcn_mfma_f32_16x16x32_bf16(vf, pa1, accO[1][s][mi], 0, 0, 0);
            }
        __builtin_amdgcn_s_setprio(0);

        __syncthreads();
    }
#undef STAGE_TILE

#pragma unroll
    for (int set = 0; set < 2; set++) {
        float l = lsum[set];
        l += __shfl_xor(l, 16);
        l += __shfl_xor(l, 32);
        float il = 1.f / l;

        const int tok = qt * 64 + w * 32 + set * 16 + l15;
#pragma unroll
        for (int s = 0; s < 2; s++)
#pragma unroll
            for (int mi = 0; mi < 4; mi++) {
                bf16x4 ov;
#pragma unroll
                for (int r = 0; r < 4; r++) ov[r] = (__bf16)(accO[set][s][mi][r] * il);
                const int row = (s * 4 + b) * 1024 + tok;
                const int c   = h * 64 + mi * 16 + quad * 4;
                const size_t off = ((size_t)(row >> 4) * 24 + (c >> 5)) * 512
                                 + ((c >> 3) & 3) * 128 + (row & 15) * 8 + (c & 7);
                *(bf16x4*)&ows[off] = ov;
            }
    }
}

// ---------------------------------------------------------------------------
extern "C" void kernel_launch(void* const* d_in, const int* in_sizes, int n_in,
                              void* d_out, int out_size, void* d_ws, size_t ws_size,
                              hipStream_t stream)
{
    const float* x1    = (const float*)d_in[0];
    const float* x2    = (const float*)d_in[1];
    const float* Wqkv  = (const float*)d_in[2];
    const float* bqkv  = (const float*)d_in[3];
    const float* Wproj = (const float*)d_in[4];
    const float* bproj = (const float*)d_in[5];
    float* out = (float*)d_out;

    const size_t qkv_elems = (size_t)2 * 4 * 12 * 1024 * 64;   // 6,291,456
    __bf16* q_ws = (__bf16*)d_ws;
    __bf16* k_ws = q_ws + qkv_elems;
    __bf16* v_ws = k_ws + qkv_elems;
    __bf16* pool = v_ws + qkv_elems;
    __bf16* o_ws = pool;                // 8192*768 tiled (attn out)
    __bf16* Wqc  = pool + 3145728;      // 2304*768 tiled (dead after QKV GEMM)
    __bf16* Xc   = (__bf16*)d_out;      // x1c | x2c tiled (scratch in out buf)

    const bool big = ws_size >= (size_t)(4 * qkv_elems + 589824) * sizeof(__bf16);
    __bf16* Wpc = big ? (pool + qkv_elems)   // past proven footprint
                      : q_ws;                // legacy: q dead after attn

    // 1) fused fp32->bf16 tiled converts via LDS transpose
    cvt4_k<<<big ? 704 : 656, 256, 0, stream>>>(x1, x2, Wqkv, Wproj, Xc, Wqc, Wpc);
    // 2) QKV GEMM, 2-buffer 32KB-LDS pipeline -> 5 blocks/CU, single round
    gemm_qkv_s<<<1152, 256, 0, stream>>>(Xc, Wqc, bqkv, q_ws, k_ws, v_ws);
    // 3) attention (round-8 proven version)
    attn_k<<<768, 128, 0, stream>>>(q_ws, k_ws, v_ws, o_ws);
    // 4) legacy tiled proj weight convert only if ws too small
    if (!big) cvt_kt<<<288, 256, 0, stream>>>(Wproj, Wpc, 73728);
    // 5) proj GEMM, 64x128 tiles, grid 6x128 = 768 = 3/CU balanced
    gemm_proj<<<dim3(6, 128), 256, 0, stream>>>(o_ws, Wpc, bproj, out);
}